// Round 13
// baseline (262.340 us; speedup 1.0000x reference)
//
#include <hip/hip_runtime.h>
#include <hip/hip_bf16.h>
#include <math.h>

#define HH 64            // hidden channels
#define EPS 1e-5f
#define STAGE_CAP 12288  // per-bucket LDS staging capacity (3x avg bucket size)
#define NBLK_SCAT 192    // partition blocks (must match between hist and scatter)
#define PER_LANE 3       // ceil(NBLK_SCAT / 64)

// ---------------------------------------------------------------- utilities
__device__ __forceinline__ int lower_bound_i(const int* a, int n, int key) {
    int lo = 0, hi = n;
    while (lo < hi) { int mid = (lo + hi) >> 1; if (a[mid] < key) lo = mid + 1; else hi = mid; }
    return lo;
}

__device__ __forceinline__ unsigned short f2bf(float f) {
    unsigned int u = __float_as_uint(f);
    unsigned int r = (u + 0x7FFFu + ((u >> 16) & 1u)) >> 16;   // RNE
    return (unsigned short)r;
}
__device__ __forceinline__ float bf2f(unsigned short b) {
    return __uint_as_float(((unsigned int)b) << 16);
}
__device__ __forceinline__ float bflo(unsigned int u) { return __uint_as_float(u << 16); }
__device__ __forceinline__ float bfhi(unsigned int u) { return __uint_as_float(u & 0xFFFF0000u); }

// ---------------------------------------------------------------- init (gsum only)
__global__ void init_kernel(float* gsum, int NG) {
    int t = blockIdx.x * blockDim.x + threadIdx.x;
    if (t < NG) gsum[t] = 0.f;
}

// pass A1: per-block histogram over buckets (LDS only, no global atomics)
__global__ __launch_bounds__(256) void hist_kernel(const int* __restrict__ dst,
        int* __restrict__ blockhist, int E, int chunk) {
    __shared__ int hist[256];
    int tid = threadIdx.x, blk = blockIdx.x;
    hist[tid] = 0;
    __syncthreads();
    int s = blk * chunk, e = s + chunk; if (e > E) e = E;
    for (int i = s + tid; i < e; i += 256) atomicAdd(&hist[dst[i] >> 8], 1);
    __syncthreads();
    blockhist[blk * 256 + tid] = hist[tid];
}

// pass A1b: single block; column-sum blockhist -> bucket totals -> exclusive scan
__global__ __launch_bounds__(256) void bucketscan_kernel(const int* __restrict__ blockhist,
        int* __restrict__ bucketbase, int NB, int E) {
    __shared__ int wsum2[4];
    int tid = threadIdx.x, lane = tid & 63, wid = tid >> 6;
    int s = 0;
    if (tid < NB) {
        for (int i = 0; i < NBLK_SCAT; ++i) s += blockhist[i * 256 + tid];
    }
    int incl = s;
    #pragma unroll
    for (int off = 1; off < 64; off <<= 1) {
        int n = __shfl_up(incl, off);
        if (lane >= off) incl += n;
    }
    if (lane == 63) wsum2[wid] = incl;
    __syncthreads();
    int wbase = 0;
    #pragma unroll
    for (int k = 0; k < 4; ++k) if (k < wid) wbase += wsum2[k];
    if (tid < NB) bucketbase[tid] = wbase + incl - s;
    if (tid == 0) bucketbase[NB] = E;
}

// pass A2: per-bucket column scan of blockhist -> per-block write cursors
__global__ __launch_bounds__(64) void offsets_kernel(const int* __restrict__ bucketbase,
        int* __restrict__ blockhist, int NB) {
    int b = blockIdx.x;
    int lane = threadIdx.x;
    int v[PER_LANE];
    int base = lane * PER_LANE;
    int s = 0;
    #pragma unroll
    for (int k = 0; k < PER_LANE; ++k) {
        int i = base + k;
        v[k] = (i < NBLK_SCAT) ? blockhist[i * 256 + b] : 0;
        s += v[k];
    }
    int incl = s;
    #pragma unroll
    for (int off = 1; off < 64; off <<= 1) {
        int n = __shfl_up(incl, off);
        if (lane >= off) incl += n;
    }
    int excl = incl - s + bucketbase[b];
    #pragma unroll
    for (int k = 0; k < PER_LANE; ++k) {
        int i = base + k;
        if (i < NBLK_SCAT) { blockhist[i * 256 + b] = excl; excl += v[k]; }
    }
}

// pass A3: scatter edges to bucket regions using LDS cursors
__global__ __launch_bounds__(256) void scatterA_kernel(const int* __restrict__ src,
        const int* __restrict__ dst, const int* __restrict__ blockhist,
        int* __restrict__ buf, int E, int chunk) {
    __shared__ int lcur[256];
    int tid = threadIdx.x, blk = blockIdx.x;
    lcur[tid] = blockhist[blk * 256 + tid];
    __syncthreads();
    int s = blk * chunk, e = s + chunk; if (e > E) e = E;
    for (int i = s + tid; i < e; i += 256) {
        int d = dst[i];
        int b = d >> 8;
        int p = atomicAdd(&lcur[b], 1);
        buf[p] = ((d & 255) << 24) | src[i];    // pack local-dst | src (src < 2^24)
    }
}

// pass B: per bucket: local degree hist + scan (writes rowstart, dis), permute to csr
__global__ __launch_bounds__(256) void bucket_to_csr_kernel(const int* __restrict__ buf,
        const int* __restrict__ bucketbase, int* __restrict__ rowstart,
        float* __restrict__ dis, int* __restrict__ csr, int N, int E) {
    __shared__ int ldeg[256];
    __shared__ int cur[256];
    __shared__ int wsum2[4];
    __shared__ int stage[STAGE_CAP];
    int b = blockIdx.x;
    int nodeStart = b << 8;
    int nodeEnd = nodeStart + 256; if (nodeEnd > N) nodeEnd = N;
    int nloc = nodeEnd - nodeStart;
    int base = bucketbase[b];
    int nE = bucketbase[b + 1] - base;
    int tid = threadIdx.x;
    int lane = tid & 63, wid = tid >> 6;
    ldeg[tid] = 0;
    __syncthreads();
    for (int i = tid; i < nE; i += 256)
        atomicAdd(&ldeg[((unsigned)buf[base + i]) >> 24], 1);
    __syncthreads();
    int d = ldeg[tid];
    int incl = d;
    #pragma unroll
    for (int off = 1; off < 64; off <<= 1) {
        int n = __shfl_up(incl, off);
        if (lane >= off) incl += n;
    }
    if (lane == 63) wsum2[wid] = incl;
    __syncthreads();
    int wbase = 0;
    #pragma unroll
    for (int k = 0; k < 4; ++k) if (k < wid) wbase += wsum2[k];
    int excl = wbase + incl - d;
    cur[tid] = excl;
    if (tid < nloc) {
        rowstart[nodeStart + tid] = base + excl;
        dis[nodeStart + tid] = rsqrtf((float)d + 1.0f);
    }
    if (b == 0 && tid == 0) rowstart[N] = E;
    __syncthreads();
    if (nE <= STAGE_CAP) {
        for (int i = tid; i < nE; i += 256) {
            int u = buf[base + i];
            int l = ((unsigned)u) >> 24;
            int p = atomicAdd(&cur[l], 1);
            stage[p] = u & 0xFFFFFF;
        }
        __syncthreads();
        for (int i = tid; i < nE; i += 256) csr[base + i] = stage[i];
    } else {
        for (int i = tid; i < nE; i += 256) {
            int u = buf[base + i];
            int l = ((unsigned)u) >> 24;
            int p = atomicAdd(&cur[l], 1);
            csr[base + p] = u & 0xFFFFFF;
        }
    }
}

// ---------------------------------------------------------------- layer 1 GEMM (IN=3) -> split bf16 tables
// one thread = 2 channels (uint store); channels <32 -> mtL, >=32 -> mtH
__global__ void mt1_kernel(const float* __restrict__ x, const float* __restrict__ W1,
                           const float* __restrict__ dis,
                           unsigned int* __restrict__ mtL2, unsigned int* __restrict__ mtH2, int N) {
    int t = blockIdx.x * blockDim.x + threadIdx.x;
    if (t < N * 32) {
        int v = t >> 5, c2 = t & 31;               // channel pair index 0..31
        float x0 = x[v * 3 + 0], x1 = x[v * 3 + 1], x2 = x[v * 3 + 2];
        float dv = dis[v];
        int c = 2 * c2;
        float ma = (x0 * W1[0 * HH + c] + x1 * W1[1 * HH + c] + x2 * W1[2 * HH + c]) * dv;
        float mb = (x0 * W1[0 * HH + c + 1] + x1 * W1[1 * HH + c + 1] + x2 * W1[2 * HH + c + 1]) * dv;
        unsigned pk = (unsigned)f2bf(ma) | ((unsigned)f2bf(mb) << 16);
        if (c2 < 16) mtL2[v * 16 + c2] = pk;
        else         mtH2[v * 16 + (c2 - 16)] = pk;
    }
}

// ---------------------------------------------------------------- 64x64 GEMM + row scale -> split bf16 tables
__global__ __launch_bounds__(256) void gemm_scale_kernel(const float* __restrict__ h,
        const float* __restrict__ W, const float* __restrict__ dis,
        unsigned short* __restrict__ mtL, unsigned short* __restrict__ mtH, int N) {
    __shared__ unsigned int wsp[HH * 34];
    __shared__ unsigned int hs2[64 * 34];
    int tid = threadIdx.x;
    int lane = tid & 63, wid = tid >> 6;
    {
        int c = tid & 63;
        for (int k2 = tid >> 6; k2 < 32; k2 += 4) {
            float a = W[(2 * k2) * HH + c];
            float b = W[(2 * k2 + 1) * HH + c];
            wsp[c * 34 + k2] = (unsigned)f2bf(a) | ((unsigned)f2bf(b) << 16);
        }
    }
    int v0 = blockIdx.x * 64;
    int nv = N - v0; if (nv > 64) nv = 64;
    for (int idx = tid; idx < 64 * 32; idx += 256) {
        int n = idx >> 5, k2 = idx & 31;
        int vsrc = v0 + ((n < nv) ? n : 0);
        float a = h[(size_t)vsrc * HH + 2 * k2];
        float b = h[(size_t)vsrc * HH + 2 * k2 + 1];
        hs2[n * 34 + k2] = (unsigned)f2bf(a) | ((unsigned)f2bf(b) << 16);
    }
    __syncthreads();
    unsigned short* tbl = (lane < 32) ? mtL : mtH;
    int cl = lane & 31;
    for (int n = wid * 16; n < wid * 16 + 16; ++n) {
        int vg = v0 + n;
        if (n >= nv) break;
        float acc = 0.f;
        #pragma unroll 4
        for (int k2g = 0; k2g < 16; ++k2g) {
            uint2 wv = *(const uint2*)&wsp[lane * 34 + 2 * k2g];
            uint2 hv = *(const uint2*)&hs2[n * 34 + 2 * k2g];
            acc = fmaf(bflo(hv.x), bflo(wv.x), acc);
            acc = fmaf(bfhi(hv.x), bfhi(wv.x), acc);
            acc = fmaf(bflo(hv.y), bflo(wv.y), acc);
            acc = fmaf(bfhi(hv.y), bfhi(wv.y), acc);
        }
        tbl[(size_t)vg * 32 + cl] = f2bf(acc * dis[vg]);
    }
}

// ---------------------------------------------------------------- half-channel gather + BN + ReLU
// Table mth = N rows x 32 channels (64B rows, 3.2MB -> per-XCD L2 resident).
// Wave per node: lane = r*16 + c4 (r=row-group 0..3, c4=channel-pair 0..15).
// Quad-row loads (4 rows x 64B per step); row groups combined via shfl_xor.
__global__ __launch_bounds__(256) void gather_bn_half_kernel(const unsigned short* __restrict__ mth,
        const int* __restrict__ rowstart, const int* __restrict__ csr_src,
        const float* __restrict__ dis, const float* __restrict__ bias,
        const float* __restrict__ gam, const float* __restrict__ beta,
        const float* __restrict__ mu, const float* __restrict__ var,
        float* __restrict__ hout, int N, int co) {
    int lane = threadIdx.x & 63, wid = threadIdx.x >> 6;
    int v = blockIdx.x * 4 + wid;
    if (v >= N) return;
    int r = lane >> 4, c4 = lane & 15;
    int start = rowstart[v], end = rowstart[v + 1];
    float ax = 0.f, ay = 0.f;
    if (r == 0) {   // self-loop term once
        unsigned u = *(const unsigned*)&mth[(size_t)v * 32 + 2 * c4];
        ax = bflo(u); ay = bfhi(u);
    }
    for (int base = start; base < end; base += 64) {
        int idx = (base + lane < end) ? csr_src[base + lane] : 0;
        int cnt = end - base; if (cnt > 64) cnt = 64;
        int j = 0;
        for (; j + 15 < cnt; j += 16) {     // 4 quad-steps, 4 loads in flight
            int p0 = __shfl(idx, j + r);
            int p1 = __shfl(idx, j + 4 + r);
            int p2 = __shfl(idx, j + 8 + r);
            int p3 = __shfl(idx, j + 12 + r);
            unsigned u0 = *(const unsigned*)&mth[(size_t)p0 * 32 + 2 * c4];
            unsigned u1 = *(const unsigned*)&mth[(size_t)p1 * 32 + 2 * c4];
            unsigned u2 = *(const unsigned*)&mth[(size_t)p2 * 32 + 2 * c4];
            unsigned u3 = *(const unsigned*)&mth[(size_t)p3 * 32 + 2 * c4];
            ax += bflo(u0); ay += bfhi(u0);
            ax += bflo(u1); ay += bfhi(u1);
            ax += bflo(u2); ay += bfhi(u2);
            ax += bflo(u3); ay += bfhi(u3);
        }
        for (; j + 3 < cnt; j += 4) {       // quad step
            int p = __shfl(idx, j + r);
            unsigned u = *(const unsigned*)&mth[(size_t)p * 32 + 2 * c4];
            ax += bflo(u); ay += bfhi(u);
        }
        if (j < cnt) {                      // masked tail (1-3 edges)
            int jr = j + r;
            int p = __shfl(idx, (jr < cnt) ? jr : 0);
            float m = (jr < cnt) ? 1.f : 0.f;
            unsigned u = *(const unsigned*)&mth[(size_t)p * 32 + 2 * c4];
            ax += m * bflo(u); ay += m * bfhi(u);
        }
    }
    // combine the 4 row groups
    ax += __shfl_xor(ax, 16); ay += __shfl_xor(ay, 16);
    ax += __shfl_xor(ax, 32); ay += __shfl_xor(ay, 32);
    if (r == 0) {
        int c = co + 2 * c4;
        float dv = dis[v];
        float vx = (ax * dv + bias[c]     - mu[c])     * rsqrtf(var[c] + EPS)     * gam[c]     + beta[c];
        float vy = (ay * dv + bias[c + 1] - mu[c + 1]) * rsqrtf(var[c + 1] + EPS) * gam[c + 1] + beta[c + 1];
        *(float2*)&hout[(size_t)v * HH + c] = make_float2(fmaxf(vx, 0.f), fmaxf(vy, 0.f));
    }
}

// ---------------------------------------------------------------- pool partial sums
__global__ __launch_bounds__(256) void pool_partial_kernel(const float* __restrict__ h,
        const int* __restrict__ batch, float* __restrict__ gsum, int N, int chunk) {
    int lane = threadIdx.x & 63, wid = threadIdx.x >> 6;
    int w = blockIdx.x * 4 + wid;
    int start = w * chunk;
    int end = start + chunk; if (end > N) end = N;
    if (start >= end) return;
    int g = batch[start];
    float acc = 0.f;
    for (int i = start; i < end; ++i) {
        int gi = batch[i];
        if (gi != g) {
            atomicAdd(&gsum[g * HH + lane], acc);
            acc = 0.f; g = gi;
        }
        acc += h[i * HH + lane];
    }
    atomicAdd(&gsum[g * HH + lane], acc);
}

// ---------------------------------------------------------------- MLP heads (+ mean divide)
__global__ __launch_bounds__(64) void heads_kernel(const float* __restrict__ gsum,
        const int* __restrict__ batch, int N,
        const float* __restrict__ thW1, const float* __restrict__ thb1,
        const float* __restrict__ thW2, const float* __restrict__ thb2,
        const float* __restrict__ lhW1, const float* __restrict__ lhb1,
        const float* __restrict__ lhW2, const float* __restrict__ lhb2,
        const float* __restrict__ shW1, const float* __restrict__ shb1,
        const float* __restrict__ shW2, const float* __restrict__ shb2,
        float* __restrict__ out, int B) {
    int g = blockIdx.x, t = threadIdx.x;
    __shared__ float ge[HH];
    __shared__ float hT[32], hL[32], hS[16];
    int lo = lower_bound_i(batch, N, g);
    int hi = lower_bound_i(batch, N, g + 1);
    float cnt = (float)(hi - lo);
    ge[t] = gsum[g * HH + t] / fmaxf(cnt, 1.0f);
    __syncthreads();
    if (t < 32) {
        float a = thb1[t];
        for (int k = 0; k < HH; ++k) a += ge[k] * thW1[k * 32 + t];
        hT[t] = fmaxf(a, 0.f);
    } else {
        int j = t - 32;
        float a = lhb1[j];
        for (int k = 0; k < HH; ++k) a += ge[k] * lhW1[k * 32 + j];
        hL[j] = fmaxf(a, 0.f);
    }
    __syncthreads();
    if (t < 16) {
        float a = shb1[t];
        for (int k = 0; k < HH; ++k) a += ge[k] * shW1[k * 16 + t];
        hS[t] = fmaxf(a, 0.f);
    }
    __syncthreads();
    if (t < 6) {
        float a = thb2[t];
        for (int j = 0; j < 32; ++j) a += hT[j] * thW2[j * 6 + t];
        out[g * 6 + t] = a;
    } else if (t >= 8 && t < 10) {
        int o = t - 8;
        float a = lhb2[o];
        for (int j = 0; j < 32; ++j) a += hL[j] * lhW2[j * 2 + o];
        out[B * 6 + g * 2 + o] = 1.f / (1.f + expf(-a));
    } else if (t == 12) {
        float a = shb2[0];
        for (int j = 0; j < 16; ++j) a += hS[j] * shW2[j];
        out[B * 8 + g] = 1.f / (1.f + expf(-a));
    }
}

// ---------------------------------------------------------------- launch
extern "C" void kernel_launch(void* const* d_in, const int* in_sizes, int n_in,
                              void* d_out, int out_size, void* d_ws, size_t ws_size,
                              hipStream_t stream) {
    const float* x   = (const float*)d_in[0];
    const int*   ei  = (const int*)d_in[1];
    const int*   bat = (const int*)d_in[2];
    const float* W1 = (const float*)d_in[3];  const float* b1 = (const float*)d_in[4];
    const float* W2 = (const float*)d_in[5];  const float* b2 = (const float*)d_in[6];
    const float* W3 = (const float*)d_in[7];  const float* b3 = (const float*)d_in[8];
    const float* bn1g = (const float*)d_in[9];  const float* bn1b = (const float*)d_in[10];
    const float* bn1m = (const float*)d_in[11]; const float* bn1v = (const float*)d_in[12];
    const float* bn2g = (const float*)d_in[13]; const float* bn2b = (const float*)d_in[14];
    const float* bn2m = (const float*)d_in[15]; const float* bn2v = (const float*)d_in[16];
    const float* bn3g = (const float*)d_in[17]; const float* bn3b = (const float*)d_in[18];
    const float* bn3m = (const float*)d_in[19]; const float* bn3v = (const float*)d_in[20];
    const float* thW1 = (const float*)d_in[21]; const float* thb1 = (const float*)d_in[22];
    const float* thW2 = (const float*)d_in[23]; const float* thb2 = (const float*)d_in[24];
    const float* lhW1 = (const float*)d_in[25]; const float* lhb1 = (const float*)d_in[26];
    const float* lhW2 = (const float*)d_in[27]; const float* lhb2 = (const float*)d_in[28];
    const float* shW1 = (const float*)d_in[29]; const float* shb1 = (const float*)d_in[30];
    const float* shW2 = (const float*)d_in[31]; const float* shb2 = (const float*)d_in[32];
    float* out = (float*)d_out;

    const int N = in_sizes[0] / 3;
    const int E = in_sizes[1] / 2;
    const int B = out_size / 9;          // 6 + 2 + 1 per graph
    const int NB = (N + 255) >> 8;       // buckets of 256 nodes
    const int* esrc = ei;
    const int* edst = ei + E;

    // workspace layout (256B aligned)
    char* w = (char*)d_ws;
    size_t off = 0;
    auto alloc = [&](size_t bytes) -> void* {
        void* p = w + off;
        off += (bytes + 255) & ~(size_t)255;
        return p;
    };
    int*   rowstart   = (int*)  alloc((size_t)(N + 1) * 4);
    float* dis        = (float*)alloc((size_t)N * 4);
    int*   csr        = (int*)  alloc((size_t)E * 4);
    int*   blockhist  = (int*)  alloc((size_t)NBLK_SCAT * 256 * 4);
    int*   bucketbase = (int*)  alloc((size_t)(NB + 1) * 4);
    float* hbuf       = (float*)alloc((size_t)N * HH * 4);
    unsigned short* mtL = (unsigned short*)alloc((size_t)N * 32 * 2);
    unsigned short* mtH = (unsigned short*)alloc((size_t)N * 32 * 2);
    float* gsum       = (float*)alloc((size_t)B * HH * 4);
    int*   bucketbuf  = (int*)hbuf;      // reuse: hbuf free until first gather (E*4 <= N*HH*4)
    (void)ws_size;

    const int TB = 256;
    const int echunk = (E + NBLK_SCAT - 1) / NBLK_SCAT;
    // CSR build: hist -> bucketscan -> offsets -> scatter -> per-bucket deg/scan/permute
    init_kernel<<<(B * HH + TB - 1) / TB, TB, 0, stream>>>(gsum, B * HH);
    hist_kernel<<<NBLK_SCAT, TB, 0, stream>>>(edst, blockhist, E, echunk);
    bucketscan_kernel<<<1, TB, 0, stream>>>(blockhist, bucketbase, NB, E);
    offsets_kernel<<<NB, 64, 0, stream>>>(bucketbase, blockhist, NB);
    scatterA_kernel<<<NBLK_SCAT, TB, 0, stream>>>(esrc, edst, blockhist, bucketbuf, E, echunk);
    bucket_to_csr_kernel<<<NB, TB, 0, stream>>>(bucketbuf, bucketbase, rowstart, dis, csr, N, E);

    int gatherBlocks = (N + 3) / 4;
    int gemmBlocks = (N + 63) / 64;
    // layer 1
    mt1_kernel<<<(N * 32 + TB - 1) / TB, TB, 0, stream>>>(x, W1, dis,
            (unsigned int*)mtL, (unsigned int*)mtH, N);
    gather_bn_half_kernel<<<gatherBlocks, TB, 0, stream>>>(mtL, rowstart, csr, dis,
            b1, bn1g, bn1b, bn1m, bn1v, hbuf, N, 0);
    gather_bn_half_kernel<<<gatherBlocks, TB, 0, stream>>>(mtH, rowstart, csr, dis,
            b1, bn1g, bn1b, bn1m, bn1v, hbuf, N, 32);
    // layer 2
    gemm_scale_kernel<<<gemmBlocks, TB, 0, stream>>>(hbuf, W2, dis, mtL, mtH, N);
    gather_bn_half_kernel<<<gatherBlocks, TB, 0, stream>>>(mtL, rowstart, csr, dis,
            b2, bn2g, bn2b, bn2m, bn2v, hbuf, N, 0);
    gather_bn_half_kernel<<<gatherBlocks, TB, 0, stream>>>(mtH, rowstart, csr, dis,
            b2, bn2g, bn2b, bn2m, bn2v, hbuf, N, 32);
    // layer 3
    gemm_scale_kernel<<<gemmBlocks, TB, 0, stream>>>(hbuf, W3, dis, mtL, mtH, N);
    gather_bn_half_kernel<<<gatherBlocks, TB, 0, stream>>>(mtL, rowstart, csr, dis,
            b3, bn3g, bn3b, bn3m, bn3v, hbuf, N, 0);
    gather_bn_half_kernel<<<gatherBlocks, TB, 0, stream>>>(mtH, rowstart, csr, dis,
            b3, bn3g, bn3b, bn3m, bn3v, hbuf, N, 32);

    // pool (gsum zeroed in init_kernel) + heads
    const int PW_BLOCKS = 512;
    int chunk = (N + PW_BLOCKS * 4 - 1) / (PW_BLOCKS * 4);
    pool_partial_kernel<<<PW_BLOCKS, TB, 0, stream>>>(hbuf, bat, gsum, N, chunk);

    heads_kernel<<<B, 64, 0, stream>>>(gsum, bat, N, thW1, thb1, thW2, thb2,
            lhW1, lhb1, lhW2, lhb2, shW1, shb1, shW2, shb2, out, B);
}